// Round 19
// baseline (530.126 us; speedup 1.0000x reference)
//
#include <hip/hip_runtime.h>

#define H512 512

typedef short bf16x8 __attribute__((ext_vector_type(8)));
typedef float f32x4  __attribute__((ext_vector_type(4)));

__device__ __forceinline__ float silu_f(float v) { return v / (1.0f + __expf(-v)); }

__device__ __forceinline__ short f2bf(float f) {   // RNE float -> bf16 bits
    unsigned u = __float_as_uint(f);
    u = (u + 0x7FFFu + ((u >> 16) & 1u)) >> 16;
    return (short)u;
}
__device__ __forceinline__ float bf2f(short s) {
    return __uint_as_float(((unsigned)(unsigned short)s) << 16);
}

// bijective XCD-chunked swizzle (m204): physical block id -> logical wg id
__device__ __forceinline__ int xcd_swz(int b, int nwg) {
    const int NX = 8;
    int q = nwg / NX, rr = nwg % NX;
    int xcd = b % NX, idx = b / NX;
    int base = (xcd < rr) ? xcd * (q + 1) : rr * (q + 1) + (xcd - rr) * q;
    return base + idx;
}

// ---------------- CSR build ----------------

__global__ void hist_kernel(const int* __restrict__ row, const int* __restrict__ col,
                            float* __restrict__ deg, int* __restrict__ cnt, int E) {
    int e = blockIdx.x * blockDim.x + threadIdx.x;
    if (e < E) {
        atomicAdd(&deg[row[e]], 1.0f);
        atomicAdd(&cnt[col[e]], 1);
    }
}

__global__ void dinv_kernel(const float* __restrict__ deg, float* __restrict__ dinv, int n) {
    int i = blockIdx.x * blockDim.x + threadIdx.x;
    if (i < n) {
        float d = deg[i];
        dinv[i] = d > 0.0f ? rsqrtf(fmaxf(d, 1e-12f)) : 0.0f;
    }
}

__global__ __launch_bounds__(256) void bsum_kernel(const int* __restrict__ cnt,
                                                   int* __restrict__ bsum, int n) {
    __shared__ int s[4];
    int i = blockIdx.x * 256 + threadIdx.x;
    int v = (i < n) ? cnt[i] : 0;
    #pragma unroll
    for (int off = 32; off; off >>= 1) v += __shfl_down(v, off, 64);
    if ((threadIdx.x & 63) == 0) s[threadIdx.x >> 6] = v;
    __syncthreads();
    if (threadIdx.x == 0) bsum[blockIdx.x] = s[0] + s[1] + s[2] + s[3];
}

__global__ __launch_bounds__(256) void bscan_kernel(const int* __restrict__ bsum,
                                                    int* __restrict__ boff, int B) {
    __shared__ int s[256];
    int tid = threadIdx.x;
    int v = (tid < B) ? bsum[tid] : 0;
    s[tid] = v;
    __syncthreads();
    #pragma unroll
    for (int off = 1; off < 256; off <<= 1) {
        int t = (tid >= off) ? s[tid - off] : 0;
        __syncthreads();
        s[tid] += t;
        __syncthreads();
    }
    if (tid < B) boff[tid] = s[tid] - v;   // exclusive
}

__global__ __launch_bounds__(256) void cscan_kernel(const int* __restrict__ cnt,
                                                    const int* __restrict__ boff,
                                                    int* __restrict__ ptr,
                                                    int* __restrict__ ptr2, int n, int B) {
    __shared__ int s[256];
    int b = blockIdx.x, tid = threadIdx.x;
    int i = b * 256 + tid;
    int v = (i < n) ? cnt[i] : 0;
    s[tid] = v;
    __syncthreads();
    #pragma unroll
    for (int off = 1; off < 256; off <<= 1) {
        int t = (tid >= off) ? s[tid - off] : 0;
        __syncthreads();
        s[tid] += t;
        __syncthreads();
    }
    int exc = boff[b] + s[tid] - v;
    if (i < n) { ptr[i] = exc; ptr2[i] = exc; }
    if (b == B - 1 && tid == 255) ptr[n] = exc + v;  // grand total
}

__global__ void scatter_kernel(const int* __restrict__ row, const int* __restrict__ col,
                               const float* __restrict__ dinv, int* __restrict__ ptr2,
                               int* __restrict__ esrc, float* __restrict__ ew, int E) {
    int e = blockIdx.x * blockDim.x + threadIdx.x;
    if (e >= E) return;
    int r = row[e], c = col[e];
    int pos = atomicAdd(&ptr2[c], 1);
    esrc[pos] = r;
    ew[pos]   = -dinv[r] * dinv[c];
}

// ---------------- converts ----------------

// Wt[n][koff+k] = bf16(W[k][n]) via 32x32 LDS tile (coalesced both sides); r7-proven.
__global__ __launch_bounds__(256) void wt_kernel(const float* __restrict__ W,
                                                 short* __restrict__ Wt, int K, int Nw,
                                                 int ldWt, int koff) {
    __shared__ float tile[32][33];
    const int tx = threadIdx.x & 31;
    const int ty = threadIdx.x >> 5;       // 0..7
    const int ntl = Nw / 32;
    const int k0 = (blockIdx.x / ntl) * 32;
    const int n0 = (blockIdx.x % ntl) * 32;
    #pragma unroll
    for (int i = 0; i < 4; ++i) {
        const int k = ty + i * 8;
        tile[k][tx] = W[(size_t)(k0 + k) * Nw + n0 + tx];
    }
    __syncthreads();
    #pragma unroll
    for (int i = 0; i < 4; ++i) {
        const int a = ty + i * 8;          // n-local
        Wt[(size_t)(n0 + a) * ldWt + koff + k0 + tx] = f2bf(tile[tx][a]);
    }
}

// xb[MPAD][256] = bf16(x), zero-padded rows
__global__ void xconv_kernel(const float* __restrict__ x, short* __restrict__ xb,
                             int Nreal, int Mpad) {
    int tid = blockIdx.x * blockDim.x + threadIdx.x;
    if (tid >= Mpad * 32) return;
    int r = tid >> 5, c8 = (tid & 31) * 8;
    bf16x8 o = {0, 0, 0, 0, 0, 0, 0, 0};
    if (r < Nreal) {
        const float4 f0 = *(const float4*)(x + (size_t)r * 256 + c8);
        const float4 f1 = *(const float4*)(x + (size_t)r * 256 + c8 + 4);
        o[0] = f2bf(f0.x); o[1] = f2bf(f0.y); o[2] = f2bf(f0.z); o[3] = f2bf(f0.w);
        o[4] = f2bf(f1.x); o[5] = f2bf(f1.y); o[6] = f2bf(f1.z); o[7] = f2bf(f1.w);
    }
    *(bf16x8*)(xb + (size_t)r * 256 + c8) = o;
}

// ------------- gather prop: G[node,:] = sum_in w * h[src,:]; zero for pad rows -------------
// 4-way unrolled edge loop (4 independent T-row loads in flight per lane).

__global__ __launch_bounds__(256) void gather_kernel(
    const int* __restrict__ ptr, const int* __restrict__ esrc,
    const float* __restrict__ ew, const short* __restrict__ T,
    short* __restrict__ U, int Nreal, int Mpad)
{
    int t = threadIdx.x;
    int node = blockIdx.x * 4 + (t >> 6);
    if (node >= Mpad) return;
    int q = (t & 63) * 8;
    if (node >= Nreal) {
        bf16x8 z = {0, 0, 0, 0, 0, 0, 0, 0};
        *(bf16x8*)(U + (size_t)node * H512 + q) = z;
        return;
    }
    float a0[8] = {}, a1[8] = {}, a2[8] = {}, a3[8] = {};
    int i = ptr[node];
    const int i1 = ptr[node + 1];
    for (; i + 4 <= i1; i += 4) {
        int s0 = esrc[i], s1 = esrc[i + 1], s2 = esrc[i + 2], s3 = esrc[i + 3];
        float w0 = ew[i], w1 = ew[i + 1], w2 = ew[i + 2], w3 = ew[i + 3];
        bf16x8 t0 = *(const bf16x8*)(T + (size_t)s0 * H512 + q);
        bf16x8 t1 = *(const bf16x8*)(T + (size_t)s1 * H512 + q);
        bf16x8 t2 = *(const bf16x8*)(T + (size_t)s2 * H512 + q);
        bf16x8 t3 = *(const bf16x8*)(T + (size_t)s3 * H512 + q);
        #pragma unroll
        for (int j = 0; j < 8; ++j) {
            a0[j] += w0 * bf2f(t0[j]);
            a1[j] += w1 * bf2f(t1[j]);
            a2[j] += w2 * bf2f(t2[j]);
            a3[j] += w3 * bf2f(t3[j]);
        }
    }
    for (; i < i1; ++i) {
        int s   = esrc[i];
        float w = ew[i];
        bf16x8 tv = *(const bf16x8*)(T + (size_t)s * H512 + q);
        #pragma unroll
        for (int j = 0; j < 8; ++j) a0[j] += w * bf2f(tv[j]);
    }
    bf16x8 o;
    #pragma unroll
    for (int j = 0; j < 8; ++j) o[j] = f2bf((a0[j] + a1[j]) + (a2[j] + a3[j]));
    *(bf16x8*)(U + (size_t)node * H512 + q) = o;
}

// ------- bf16 MFMA GEMM: 3-deep pipelined, counted-vmcnt-never-drains (T3+T4+T5) -------
// 512 thr = 8 waves (4M x 2N), tile 256M x 128N, BK=64, wave out 64x64 (acc 64 AGPR).
// LDS 144KB = 3 bufs x (A 256x64 | B 128x64), tile t -> buf t%3.
// Schedule per tile t (2 phases, ks=0/1):
//   phase: 8 ds_read (A4+B4, XOR-swz) ; 3 stage calls for tile t+2 -> buf (t+2)%3
//          (provably idle: freed when t-1 finished) ; s_barrier ; lgkmcnt(0)+SGB ;
//          setprio(1) 16 MFMA setprio(0) ; [ks1: vmcnt(t+2<nt?6:0)] ; s_barrier.
// PUBLISH PROOF: tile t+1's 6 stage loads are retired by EVERY wave's own vmcnt
// BEFORE the closing barrier of tile t => all waves' ds_reads of tile t+1 (issued
// after that barrier) see landed data. Steady-state vmcnt leaves 6 in flight --
// the pipeline NEVER drains (m218: counted-vs-drain = +38-73%).
// Fragment layouts / swizzle / epilogue identical to the r7/r13 proven pieces.

template<int SILU, int F32OUT>
__global__ __launch_bounds__(512, 2) void mfma_gemm(
    const short* __restrict__ A0, const short* __restrict__ A1, int ksplit, int lda,
    const short* __restrict__ Bt, int ldb,
    void* __restrict__ Cout, int ldc,
    const float* __restrict__ bias, int Mreal, int K, int gx)
{
    __shared__ alignas(16) short lds[3 * 24576];   // 144 KB

    const int t    = threadIdx.x;
    const int lane = t & 63;
    const int wid  = t >> 6;          // 0..7

    const int wg = xcd_swz(blockIdx.x, gridDim.x);
    const int m0 = (wg / gx) * 256;
    const int n0 = (wg % gx) * 128;

    const int wm = wid >> 1;          // 0..3 -> rows wm*64..+63
    const int wn = wid & 1;           // 0..1 -> cols wn*64..+63

    const int srow = lane >> 3;               // 0..7
    const int scol = (lane & 7) * 16;         // byte col 0..112
    const int cel  = (scol ^ (srow << 4)) >> 1;  // inverse-swizzled src element

    const int r = lane & 15;
    const int g = lane >> 4;
    const int nt = K >> 6;            // 4 / 16 / 8 in our uses

    f32x4 acc[4][4];
    #pragma unroll
    for (int m = 0; m < 4; ++m)
        #pragma unroll
        for (int n = 0; n < 4; ++n)
            acc[m][n] = (f32x4){0.f, 0.f, 0.f, 0.f};

    auto stageA = [&](int buf, int kt, int i) {   // one call = 8 rows/wave (8KB total)
        const int k0 = kt * 64;
        const short* Ab = (k0 < ksplit) ? (A0 + k0) : (A1 + (k0 - ksplit));
        const int r0 = wid * 32 + i * 8;
        const short* ga = Ab + (size_t)(m0 + r0 + srow) * lda + cel;
        __builtin_amdgcn_global_load_lds(
            (const __attribute__((address_space(1))) void*)ga,
            (__attribute__((address_space(3))) void*)(lds + buf * 24576 + r0 * 64), 16, 0, 0);
    };
    auto stageB = [&](int buf, int kt, int j) {
        const int k0 = kt * 64;
        const int r0 = wid * 16 + j * 8;
        const short* gb = Bt + (size_t)(n0 + r0 + srow) * ldb + (k0 + cel);
        __builtin_amdgcn_global_load_lds(
            (const __attribute__((address_space(1))) void*)gb,
            (__attribute__((address_space(3))) void*)(lds + buf * 24576 + 16384 + r0 * 64), 16, 0, 0);
    };

    // prologue: tiles 0 (buf0), 1 (buf1) = 12 loads; retire tile 0 (leave tile 1's 6)
    #pragma unroll
    for (int i = 0; i < 4; ++i) stageA(0, 0, i);
    stageB(0, 0, 0); stageB(0, 0, 1);
    #pragma unroll
    for (int i = 0; i < 4; ++i) stageA(1, 1, i);
    stageB(1, 1, 0); stageB(1, 1, 1);
    asm volatile("s_waitcnt vmcnt(6)" ::: "memory");
    __builtin_amdgcn_sched_barrier(0);
    __builtin_amdgcn_s_barrier();     // publish tile 0

    for (int tt = 0; tt < nt; ++tt) {
        const short* Ab = lds + (tt % 3) * 24576;
        const short* Bb = Ab + 16384;
        const int sbuf = (tt + 2) % 3;
        #pragma unroll
        for (int ks = 0; ks < 2; ++ks) {
            bf16x8 af[4], bfv[4];
            #pragma unroll
            for (int m = 0; m < 4; ++m) {
                const int rowA = wm * 64 + m * 16 + r;
                const int cb   = (ks * 64 + g * 16) ^ ((rowA & 7) << 4);
                af[m] = *(const bf16x8*)((const char*)Ab + rowA * 128 + cb);
            }
            #pragma unroll
            for (int n = 0; n < 4; ++n) {
                const int rowB = wn * 64 + n * 16 + r;
                const int cb   = (ks * 64 + g * 16) ^ ((rowB & 7) << 4);
                bfv[n] = *(const bf16x8*)((const char*)Bb + rowB * 128 + cb);
            }
            if (tt + 2 < nt) {
                if (ks == 0) { stageA(sbuf, tt + 2, 0); stageA(sbuf, tt + 2, 1); stageB(sbuf, tt + 2, 0); }
                else         { stageA(sbuf, tt + 2, 2); stageA(sbuf, tt + 2, 3); stageB(sbuf, tt + 2, 1); }
            }
            __builtin_amdgcn_sched_barrier(0);
            __builtin_amdgcn_s_barrier();
            asm volatile("s_waitcnt lgkmcnt(0)" ::: "memory");
            __builtin_amdgcn_sched_barrier(0);     // rule #18: fence MFMA after lgkmcnt
            __builtin_amdgcn_s_setprio(1);
            #pragma unroll
            for (int m = 0; m < 4; ++m)
                #pragma unroll
                for (int n = 0; n < 4; ++n)
                    acc[m][n] = __builtin_amdgcn_mfma_f32_16x16x32_bf16(
                        af[m], bfv[n], acc[m][n], 0, 0, 0);
            __builtin_amdgcn_s_setprio(0);
            __builtin_amdgcn_sched_barrier(0);
            if (ks == 1 && tt + 1 < nt) {           // publish tile tt+1 before its reads
                if (tt + 2 < nt) asm volatile("s_waitcnt vmcnt(6)" ::: "memory");
                else             asm volatile("s_waitcnt vmcnt(0)" ::: "memory");
                __builtin_amdgcn_sched_barrier(0);
            }
            __builtin_amdgcn_s_barrier();
        }
    }

    // ---- epilogue ----
    float bb2[4];
    #pragma unroll
    for (int n = 0; n < 4; ++n) bb2[n] = bias[n0 + wn * 64 + n * 16 + r];

    if (F32OUT) {
        #pragma unroll
        for (int m = 0; m < 4; ++m)
            #pragma unroll
            for (int j = 0; j < 4; ++j) {
                const int rr = m0 + wm * 64 + m * 16 + g * 4 + j;
                #pragma unroll
                for (int n = 0; n < 4; ++n) {
                    float v = acc[m][n][j] + bb2[n];
                    if (SILU) v = silu_f(v);
                    if (rr < Mreal)
                        ((float*)Cout)[(size_t)rr * ldc + n0 + wn * 64 + n * 16 + r] = v;
                }
            }
    } else {
        __syncthreads();                    // full drain; reuse lds as fs[256][128] bf16
        short* fs = (short*)lds;
        #pragma unroll
        for (int m = 0; m < 4; ++m)
            #pragma unroll
            for (int j = 0; j < 4; ++j) {
                const int row = wm * 64 + m * 16 + g * 4 + j;   // 0..255
                const int rot = (row & 15) << 3;
                #pragma unroll
                for (int n = 0; n < 4; ++n) {
                    float v = acc[m][n][j] + bb2[n];
                    if (SILU) v = silu_f(v);
                    const int col = wn * 64 + n * 16 + r;       // 0..127
                    fs[row * 128 + ((col + rot) & 127)] = f2bf(v);
                }
            }
        __syncthreads();
        const int rr   = t >> 1;            // 0..255
        const int hf   = t & 1;
        const int rot2 = (rr & 15) << 3;
        const size_t gr = (size_t)(m0 + rr);
        #pragma unroll
        for (int c8 = 0; c8 < 8; ++c8) {
            const int cbase = hf * 64 + c8 * 8;
            const int cl    = (cbase + rot2) & 127;
            bf16x8 v8 = *(const bf16x8*)&fs[rr * 128 + cl];
            *(bf16x8*)((short*)Cout + gr * ldc + n0 + cbase) = v8;
        }
    }
}

// ---------------- launcher ----------------
// Workspace (MPAD=50176): h0,h1,G bf16 51.4 MB each = 154.2 MB
//   + wti 0.26 + wtf 2.10 + wto 0.26 + CSR ~4.5  ~= 161 MB.  xb aliases G.

extern "C" void kernel_launch(void* const* d_in, const int* in_sizes, int n_in,
                              void* d_out, int out_size, void* d_ws, size_t ws_size,
                              hipStream_t stream)
{
    const float* x      = (const float*)d_in[0];
    const int*   ei     = (const int*)  d_in[1];
    const float* in_w   = (const float*)d_in[2];
    const float* in_b   = (const float*)d_in[3];
    const float* conv_w = (const float*)d_in[4];
    const float* conv_b = (const float*)d_in[5];
    const float* out_w  = (const float*)d_in[6];
    const float* out_b  = (const float*)d_in[7];

    const int N = in_sizes[0] / 256;           // 50000
    const int E = in_sizes[1] / 2;             // 400000
    const int MPAD = ((N + 255) / 256) * 256;  // 50176
    const int* row = ei;
    const int* col = ei + E;

    char* p = (char*)d_ws;
    short* h0 = (short*)p; p += (size_t)MPAD * H512 * 2;
    short* h1 = (short*)p; p += (size_t)MPAD * H512 * 2;
    short* G  = (short*)p; p += (size_t)MPAD * H512 * 2;
    short* xb = G;  // alias: xb dead before G is first written
    short* wti = (short*)p; p += (size_t)512 * 256 * 2;       // in_w^T  [512][256]
    short* wtf = (short*)p; p += (size_t)2 * 512 * 1024 * 2;  // fused [l][512 out][1024 k]
    short* wto = (short*)p; p += (size_t)256 * 512 * 2;       // out_w^T [256][512]
    float* deg  = (float*)p; p += (size_t)N * 4;
    float* dinv = (float*)p; p += (size_t)N * 4;
    float* ew   = (float*)p; p += (size_t)E * 4;
    int*   cnt  = (int*)p;   p += (size_t)N * 4;
    int*   ptr  = (int*)p;   p += (size_t)(N + 4) * 4;
    int*   ptr2 = (int*)p;   p += (size_t)N * 4;
    int*   esrc = (int*)p;   p += (size_t)E * 4;
    int*   bsum = (int*)p;   p += (size_t)256 * 4;
    int*   boff = (int*)p;   p += (size_t)256 * 4;

    const int NB = (N + 255) / 256;            // 196 scan blocks

    // CSR build
    hipMemsetAsync(deg, 0, (size_t)N * sizeof(float), stream);
    hipMemsetAsync(cnt, 0, (size_t)N * sizeof(int), stream);
    hist_kernel<<<(E + 255) / 256, 256, 0, stream>>>(row, col, deg, cnt, E);
    dinv_kernel<<<(N + 255) / 256, 256, 0, stream>>>(deg, dinv, N);
    bsum_kernel <<<NB, 256, 0, stream>>>(cnt, bsum, N);
    bscan_kernel<<<1, 256, 0, stream>>>(bsum, boff, NB);
    cscan_kernel<<<NB, 256, 0, stream>>>(cnt, boff, ptr, ptr2, N, NB);
    scatter_kernel<<<(E + 255) / 256, 256, 0, stream>>>(row, col, dinv, ptr2, esrc, ew, E);

    // weight converts: transposed bf16 (k-contiguous); fused [W0;W1] stacked along k
    wt_kernel<<<(256 / 32) * (512 / 32), 256, 0, stream>>>(in_w, wti, 256, 512, 256, 0);
    for (int l = 0; l < 2; ++l)
        for (int j = 0; j < 2; ++j)
            wt_kernel<<<(512 / 32) * (512 / 32), 256, 0, stream>>>(
                conv_w + (size_t)(l * 2 + j) * 512 * 512,
                wtf + (size_t)l * 512 * 1024, 512, 512, 1024, j * 512);
    wt_kernel<<<(512 / 32) * (256 / 32), 256, 0, stream>>>(out_w, wto, 512, 256, 512, 0);
    xconv_kernel<<<(MPAD * 32 + 255) / 256, 256, 0, stream>>>(x, xb, N, MPAD);

    const int mt = MPAD / 256;                 // 196

    // h0 = silu(x @ in_w + in_b)        K=256, Nw=512 -> gx=4
    mfma_gemm<1, 0><<<dim3(4 * mt), 512, 0, stream>>>(
        xb, xb, 256, 256, wti, 256, h0, H512, in_b, N, 256, 4);

    short* hc = h0;
    short* hn = h1;
    for (int l = 0; l < 2; ++l) {
        // G = Lhat @ hc  (gather, zero-pads rows >= N)
        gather_kernel<<<(MPAD + 3) / 4, 256, 0, stream>>>(ptr, esrc, ew, hc, G, N, MPAD);
        // hn = silu([hc | G] @ [W0;W1] + b)   K=1024, split at 512, gx=4
        mfma_gemm<1, 0><<<dim3(4 * mt), 512, 0, stream>>>(
            hc, G, 512, H512, wtf + (size_t)l * 512 * 1024, 1024,
            hn, H512, conv_b + (size_t)l * H512, N, 1024, 4);
        short* tmp = hc; hc = hn; hn = tmp;
    }

    // out = hc @ out_w + out_b   (fp32, guarded)     K=512, Nw=256 -> gx=2
    mfma_gemm<0, 1><<<dim3(2 * mt), 512, 0, stream>>>(
        hc, hc, 512, H512, wto, 512, d_out, 256, out_b, N, 512, 2);
}

// Round 20
// 434.778 us; speedup vs baseline: 1.2193x; 1.2193x over previous
//
#include <hip/hip_runtime.h>

#define H512 512

typedef short bf16x8 __attribute__((ext_vector_type(8)));
typedef float f32x4  __attribute__((ext_vector_type(4)));

__device__ __forceinline__ float silu_f(float v) { return v / (1.0f + __expf(-v)); }

__device__ __forceinline__ short f2bf(float f) {   // RNE float -> bf16 bits
    unsigned u = __float_as_uint(f);
    u = (u + 0x7FFFu + ((u >> 16) & 1u)) >> 16;
    return (short)u;
}
__device__ __forceinline__ float bf2f(short s) {
    return __uint_as_float(((unsigned)(unsigned short)s) << 16);
}

// bijective XCD-chunked swizzle (m204): physical block id -> logical wg id
__device__ __forceinline__ int xcd_swz(int b, int nwg) {
    const int NX = 8;
    int q = nwg / NX, rr = nwg % NX;
    int xcd = b % NX, idx = b / NX;
    int base = (xcd < rr) ? xcd * (q + 1) : rr * (q + 1) + (xcd - rr) * q;
    return base + idx;
}

// ---------------- CSR build ----------------

__global__ void hist_kernel(const int* __restrict__ row, const int* __restrict__ col,
                            float* __restrict__ deg, int* __restrict__ cnt, int E) {
    int e = blockIdx.x * blockDim.x + threadIdx.x;
    if (e < E) {
        atomicAdd(&deg[row[e]], 1.0f);
        atomicAdd(&cnt[col[e]], 1);
    }
}

__global__ void dinv_kernel(const float* __restrict__ deg, float* __restrict__ dinv, int n) {
    int i = blockIdx.x * blockDim.x + threadIdx.x;
    if (i < n) {
        float d = deg[i];
        dinv[i] = d > 0.0f ? rsqrtf(fmaxf(d, 1e-12f)) : 0.0f;
    }
}

__global__ __launch_bounds__(256) void bsum_kernel(const int* __restrict__ cnt,
                                                   int* __restrict__ bsum, int n) {
    __shared__ int s[4];
    int i = blockIdx.x * 256 + threadIdx.x;
    int v = (i < n) ? cnt[i] : 0;
    #pragma unroll
    for (int off = 32; off; off >>= 1) v += __shfl_down(v, off, 64);
    if ((threadIdx.x & 63) == 0) s[threadIdx.x >> 6] = v;
    __syncthreads();
    if (threadIdx.x == 0) bsum[blockIdx.x] = s[0] + s[1] + s[2] + s[3];
}

__global__ __launch_bounds__(256) void bscan_kernel(const int* __restrict__ bsum,
                                                    int* __restrict__ boff, int B) {
    __shared__ int s[256];
    int tid = threadIdx.x;
    int v = (tid < B) ? bsum[tid] : 0;
    s[tid] = v;
    __syncthreads();
    #pragma unroll
    for (int off = 1; off < 256; off <<= 1) {
        int t = (tid >= off) ? s[tid - off] : 0;
        __syncthreads();
        s[tid] += t;
        __syncthreads();
    }
    if (tid < B) boff[tid] = s[tid] - v;   // exclusive
}

__global__ __launch_bounds__(256) void cscan_kernel(const int* __restrict__ cnt,
                                                    const int* __restrict__ boff,
                                                    int* __restrict__ ptr,
                                                    int* __restrict__ ptr2, int n, int B) {
    __shared__ int s[256];
    int b = blockIdx.x, tid = threadIdx.x;
    int i = b * 256 + tid;
    int v = (i < n) ? cnt[i] : 0;
    s[tid] = v;
    __syncthreads();
    #pragma unroll
    for (int off = 1; off < 256; off <<= 1) {
        int t = (tid >= off) ? s[tid - off] : 0;
        __syncthreads();
        s[tid] += t;
        __syncthreads();
    }
    int exc = boff[b] + s[tid] - v;
    if (i < n) { ptr[i] = exc; ptr2[i] = exc; }
    if (b == B - 1 && tid == 255) ptr[n] = exc + v;  // grand total
}

__global__ void scatter_kernel(const int* __restrict__ row, const int* __restrict__ col,
                               const float* __restrict__ dinv, int* __restrict__ ptr2,
                               int* __restrict__ esrc, float* __restrict__ ew, int E) {
    int e = blockIdx.x * blockDim.x + threadIdx.x;
    if (e >= E) return;
    int r = row[e], c = col[e];
    int pos = atomicAdd(&ptr2[c], 1);
    esrc[pos] = r;
    ew[pos]   = -dinv[r] * dinv[c];
}

// ---------------- converts ----------------

// Pre-shuffle weight W[k][n] (fp32, k-major) into MFMA fragment order (2x2 wave
// grid): chunk = ((n128*2+wn)*ktot + ktoff+ktl)*8 + ks*4 + nfrag, 512 elems each
// (64 lanes x bf16x8); lane(r,g) holds col = n128*128+wn*64+nfrag*16+r,
// k = ktl*64+ks*32+g*8 .. +8.  Makes GEMM loadB a contiguous 1KB/wave load.
__device__ __forceinline__ void bfshuf_body(const float* W, short* Bf,
                                            int Ksrc, int Nw, int ktot, int ktoff,
                                            int tid) {
    const int nchunks_src = (Nw / 128) * 2 * (Ksrc / 64) * 8;
    if (tid >= nchunks_src * 64) return;
    int lane = tid & 63;  int rest = tid >> 6;
    int nfrag = rest & 3; rest >>= 2;
    int ks    = rest & 1; rest >>= 1;
    int ktl   = rest % (Ksrc / 64); rest /= (Ksrc / 64);
    int wn    = rest & 1;
    int n128  = rest >> 1;
    int r = lane & 15, g = lane >> 4;
    int colw = n128 * 128 + wn * 64 + nfrag * 16 + r;
    int k0   = ktl * 64 + ks * 32 + g * 8;
    size_t dst = ((size_t)(((n128 * 2 + wn) * ktot + ktoff + ktl) * 8 + ks * 4 + nfrag) * 64 + lane) * 8;
    bf16x8 o;
    #pragma unroll
    for (int j = 0; j < 8; ++j) o[j] = f2bf(W[(size_t)(k0 + j) * Nw + colw]);
    *(bf16x8*)(Bf + dst) = o;
}

__global__ void bfshuf_kernel(const float* __restrict__ W, short* __restrict__ Bf,
                              int Ksrc, int Nw, int ktot, int ktoff) {
    bfshuf_body(W, Bf, Ksrc, Nw, ktot, ktoff, blockIdx.x * blockDim.x + threadIdx.x);
}

// batched conv variant: blockIdx.y = l*2+j; dst layer = y>>1, ktoff = (y&1)*8
__global__ void bfshuf4_kernel(const float* __restrict__ Wall, short* __restrict__ Bf) {
    int li = blockIdx.y;
    bfshuf_body(Wall + (size_t)li * 512 * 512,
                Bf + (size_t)(li >> 1) * 512 * 1024,
                512, 512, 16, (li & 1) * 8,
                blockIdx.x * blockDim.x + threadIdx.x);
}

// xb[MPAD][256] = bf16(x), zero-padded rows
__global__ void xconv_kernel(const float* __restrict__ x, short* __restrict__ xb,
                             int Nreal, int Mpad) {
    int tid = blockIdx.x * blockDim.x + threadIdx.x;
    if (tid >= Mpad * 32) return;
    int r = tid >> 5, c8 = (tid & 31) * 8;
    bf16x8 o = {0, 0, 0, 0, 0, 0, 0, 0};
    if (r < Nreal) {
        const float4 f0 = *(const float4*)(x + (size_t)r * 256 + c8);
        const float4 f1 = *(const float4*)(x + (size_t)r * 256 + c8 + 4);
        o[0] = f2bf(f0.x); o[1] = f2bf(f0.y); o[2] = f2bf(f0.z); o[3] = f2bf(f0.w);
        o[4] = f2bf(f1.x); o[5] = f2bf(f1.y); o[6] = f2bf(f1.z); o[7] = f2bf(f1.w);
    }
    *(bf16x8*)(xb + (size_t)r * 256 + c8) = o;
}

// ------------- gather prop: G[node,:] = sum_in w * h[src,:]; zero for pad rows -------------
// 8-way unrolled edge loop: 8 independent T-row loads + accumulator sets in
// flight per lane (latency-bound on L3-served random reads; r15's 4-way was +11us).

__global__ __launch_bounds__(256) void gather_kernel(
    const int* __restrict__ ptr, const int* __restrict__ esrc,
    const float* __restrict__ ew, const short* __restrict__ T,
    short* __restrict__ U, int Nreal, int Mpad)
{
    int t = threadIdx.x;
    int node = blockIdx.x * 4 + (t >> 6);
    if (node >= Mpad) return;
    int q = (t & 63) * 8;
    if (node >= Nreal) {
        bf16x8 z = {0, 0, 0, 0, 0, 0, 0, 0};
        *(bf16x8*)(U + (size_t)node * H512 + q) = z;
        return;
    }
    float a0[8] = {}, a1[8] = {}, a2[8] = {}, a3[8] = {};
    float a4[8] = {}, a5[8] = {}, a6[8] = {}, a7[8] = {};
    int i = ptr[node];
    const int i1 = ptr[node + 1];
    for (; i + 8 <= i1; i += 8) {
        int s0 = esrc[i],     s1 = esrc[i + 1], s2 = esrc[i + 2], s3 = esrc[i + 3];
        int s4 = esrc[i + 4], s5 = esrc[i + 5], s6 = esrc[i + 6], s7 = esrc[i + 7];
        float w0 = ew[i],     w1 = ew[i + 1], w2 = ew[i + 2], w3 = ew[i + 3];
        float w4 = ew[i + 4], w5 = ew[i + 5], w6 = ew[i + 6], w7 = ew[i + 7];
        bf16x8 t0 = *(const bf16x8*)(T + (size_t)s0 * H512 + q);
        bf16x8 t1 = *(const bf16x8*)(T + (size_t)s1 * H512 + q);
        bf16x8 t2 = *(const bf16x8*)(T + (size_t)s2 * H512 + q);
        bf16x8 t3 = *(const bf16x8*)(T + (size_t)s3 * H512 + q);
        bf16x8 t4 = *(const bf16x8*)(T + (size_t)s4 * H512 + q);
        bf16x8 t5 = *(const bf16x8*)(T + (size_t)s5 * H512 + q);
        bf16x8 t6 = *(const bf16x8*)(T + (size_t)s6 * H512 + q);
        bf16x8 t7 = *(const bf16x8*)(T + (size_t)s7 * H512 + q);
        #pragma unroll
        for (int j = 0; j < 8; ++j) {
            a0[j] += w0 * bf2f(t0[j]);
            a1[j] += w1 * bf2f(t1[j]);
            a2[j] += w2 * bf2f(t2[j]);
            a3[j] += w3 * bf2f(t3[j]);
            a4[j] += w4 * bf2f(t4[j]);
            a5[j] += w5 * bf2f(t5[j]);
            a6[j] += w6 * bf2f(t6[j]);
            a7[j] += w7 * bf2f(t7[j]);
        }
    }
    for (; i + 4 <= i1; i += 4) {
        int s0 = esrc[i], s1 = esrc[i + 1], s2 = esrc[i + 2], s3 = esrc[i + 3];
        float w0 = ew[i], w1 = ew[i + 1], w2 = ew[i + 2], w3 = ew[i + 3];
        bf16x8 t0 = *(const bf16x8*)(T + (size_t)s0 * H512 + q);
        bf16x8 t1 = *(const bf16x8*)(T + (size_t)s1 * H512 + q);
        bf16x8 t2 = *(const bf16x8*)(T + (size_t)s2 * H512 + q);
        bf16x8 t3 = *(const bf16x8*)(T + (size_t)s3 * H512 + q);
        #pragma unroll
        for (int j = 0; j < 8; ++j) {
            a0[j] += w0 * bf2f(t0[j]);
            a1[j] += w1 * bf2f(t1[j]);
            a2[j] += w2 * bf2f(t2[j]);
            a3[j] += w3 * bf2f(t3[j]);
        }
    }
    for (; i < i1; ++i) {
        int s   = esrc[i];
        float w = ew[i];
        bf16x8 tv = *(const bf16x8*)(T + (size_t)s * H512 + q);
        #pragma unroll
        for (int j = 0; j < 8; ++j) a0[j] += w * bf2f(tv[j]);
    }
    bf16x8 o;
    #pragma unroll
    for (int j = 0; j < 8; ++j)
        o[j] = f2bf(((a0[j] + a1[j]) + (a2[j] + a3[j])) + ((a4[j] + a5[j]) + (a6[j] + a7[j])));
    *(bf16x8*)(U + (size_t)node * H512 + q) = o;
}

// ---------------- bf16 MFMA GEMM (r16, best-known: 84us conv) ----------------
// A-only LDS dbuf, B frag-shuffled single-buffer regs.  Schedule per step tt:
//   vmcnt(12) [steady no-op; retires A(tt) at prologue; vmcnt(8) last step]
//   s_barrier | mmstep (compiler waits cover B(tt)) | s_barrier
//   loadB(tt+1) BEFORE stageA(tt+2)  (so the next step's b-wait never retires
//   a fresh A — in-order-retirement ledger, see r16 notes)

template<int SILU, int F32OUT>
__global__ __launch_bounds__(256, 4) void mfma_gemm(
    const short* __restrict__ A0, const short* __restrict__ A1, int ksplit, int lda,
    const short* __restrict__ Bf,
    void* __restrict__ Cout, int ldc,
    const float* __restrict__ bias, int Mreal, int K, int gx)
{
    __shared__ alignas(16) short As[2][128 * 64];   // 32 KB; epilogue reuses as [128][128]

    const int t    = threadIdx.x;
    const int lane = t & 63;
    const int wid  = t >> 6;

    const int wg = xcd_swz(blockIdx.x, gridDim.x);
    const int m0 = (wg / gx) * 128;
    const int n0 = (wg % gx) * 128;

    const int wm = wid >> 1;
    const int wn = wid & 1;

    const int srow  = lane >> 3;            // 0..7
    const int scol  = (lane & 7) * 16;      // byte col, 0..112
    const int corig = scol ^ (srow << 4);   // inverse-swizzled source byte col
    const int cel   = corig >> 1;           // source element offset

    const int r = lane & 15;
    const int g = lane >> 4;

    const int nt = K >> 6;                  // 4 / 16 / 8 in our uses (always >= 2)
    const short* Bw = Bf + (size_t)((n0 >> 7) * 2 + wn) * nt * 4096;

    f32x4 acc[4][4];
    #pragma unroll
    for (int m = 0; m < 4; ++m)
        #pragma unroll
        for (int n = 0; n < 4; ++n)
            acc[m][n] = (f32x4){0.f, 0.f, 0.f, 0.f};

    auto stageA = [&](int buf, int kt) {
        const int k0 = kt * 64;
        const short* Abase = (k0 < ksplit) ? (A0 + k0) : (A1 + (k0 - ksplit));
        #pragma unroll
        for (int i = 0; i < 4; ++i) {
            const int r0 = (wid * 4 + i) * 8;
            const short* ga = Abase + (size_t)(m0 + r0 + srow) * lda + cel;
            __builtin_amdgcn_global_load_lds(
                (const __attribute__((address_space(1))) void*)ga,
                (__attribute__((address_space(3))) void*)(As[buf] + r0 * 64), 16, 0, 0);
        }
    };
    auto loadB = [&](bf16x8* bb, int kt) {
        #pragma unroll
        for (int ks = 0; ks < 2; ++ks)
            #pragma unroll
            for (int n = 0; n < 4; ++n)
                bb[ks * 4 + n] = *(const bf16x8*)(Bw + (size_t)(kt * 8 + ks * 4 + n) * 512 + lane * 8);
    };
    auto mmstep = [&](int cur, const bf16x8* bb) {
        const short* Ab = As[cur];
        #pragma unroll
        for (int ks = 0; ks < 2; ++ks) {
            bf16x8 af[4];
            #pragma unroll
            for (int m = 0; m < 4; ++m) {
                const int rowA = wm * 64 + m * 16 + r;
                const int cb   = (ks * 64 + g * 16) ^ ((rowA & 7) << 4);
                af[m] = *(const bf16x8*)((const char*)Ab + rowA * 128 + cb);
            }
            #pragma unroll
            for (int m = 0; m < 4; ++m)
                #pragma unroll
                for (int n = 0; n < 4; ++n)
                    acc[m][n] = __builtin_amdgcn_mfma_f32_16x16x32_bf16(
                        af[m], bb[ks * 4 + n], acc[m][n], 0, 0, 0);
        }
    };

    bf16x8 b[8];
    stageA(0, 0);
    stageA(1, 1);
    loadB(b, 0);
    __builtin_amdgcn_sched_barrier(0);

    for (int tt = 0; tt < nt; ++tt) {
        if (tt + 1 < nt) asm volatile("s_waitcnt vmcnt(12)" ::: "memory");
        else             asm volatile("s_waitcnt vmcnt(8)"  ::: "memory");
        __builtin_amdgcn_s_barrier();
        __builtin_amdgcn_sched_barrier(0);
        mmstep(tt & 1, b);
        __builtin_amdgcn_sched_barrier(0);
        __builtin_amdgcn_s_barrier();
        if (tt + 1 < nt) loadB(b, tt + 1);          // B first (see ledger note)
        if (tt + 2 < nt) stageA(tt & 1, tt + 2);
        __builtin_amdgcn_sched_barrier(0);
    }

    // ---- epilogue ----
    float bb2[4];
    #pragma unroll
    for (int n = 0; n < 4; ++n) bb2[n] = bias[n0 + wn * 64 + n * 16 + r];

    if (F32OUT) {
        #pragma unroll
        for (int m = 0; m < 4; ++m)
            #pragma unroll
            for (int j = 0; j < 4; ++j) {
                const int rr = m0 + wm * 64 + m * 16 + g * 4 + j;
                #pragma unroll
                for (int n = 0; n < 4; ++n) {
                    float v = acc[m][n][j] + bb2[n];
                    if (SILU) v = silu_f(v);
                    if (rr < Mreal)
                        ((float*)Cout)[(size_t)rr * ldc + n0 + wn * 64 + n * 16 + r] = v;
                }
            }
    } else {
        __syncthreads();                    // full drain; reuse As as [128][128] bf16
        short* fs = (short*)As;
        #pragma unroll
        for (int m = 0; m < 4; ++m)
            #pragma unroll
            for (int j = 0; j < 4; ++j) {
                const int row = wm * 64 + m * 16 + g * 4 + j;
                const int rot = (row & 15) << 3;
                #pragma unroll
                for (int n = 0; n < 4; ++n) {
                    float v = acc[m][n][j] + bb2[n];
                    if (SILU) v = silu_f(v);
                    const int col = wn * 64 + n * 16 + r;
                    fs[row * 128 + ((col + rot) & 127)] = f2bf(v);
                }
            }
        __syncthreads();
        const int rr   = t >> 1;
        const int hf   = t & 1;
        const int rot2 = (rr & 15) << 3;
        const size_t gr = (size_t)(m0 + rr);
        #pragma unroll
        for (int c8 = 0; c8 < 8; ++c8) {
            const int cbase = hf * 64 + c8 * 8;
            const int cl    = (cbase + rot2) & 127;
            bf16x8 v8 = *(const bf16x8*)&fs[rr * 128 + cl];
            *(bf16x8*)((short*)Cout + gr * ldc + n0 + cbase) = v8;
        }
    }
}

// ---------------- launcher ----------------
// Workspace (MPAD=50048): h0,h1,G bf16 51.25 MB each = 153.8 MB
//   + bfi 0.26 + bfc 2.10 + bfo 0.26 + CSR ~4.5  ~= 161 MB.  xb aliases G.

extern "C" void kernel_launch(void* const* d_in, const int* in_sizes, int n_in,
                              void* d_out, int out_size, void* d_ws, size_t ws_size,
                              hipStream_t stream)
{
    const float* x      = (const float*)d_in[0];
    const int*   ei     = (const int*)  d_in[1];
    const float* in_w   = (const float*)d_in[2];
    const float* in_b   = (const float*)d_in[3];
    const float* conv_w = (const float*)d_in[4];
    const float* conv_b = (const float*)d_in[5];
    const float* out_w  = (const float*)d_in[6];
    const float* out_b  = (const float*)d_in[7];

    const int N = in_sizes[0] / 256;           // 50000
    const int E = in_sizes[1] / 2;             // 400000
    const int MPAD = ((N + 127) / 128) * 128;  // 50048
    const int* row = ei;
    const int* col = ei + E;

    char* p = (char*)d_ws;
    short* h0 = (short*)p; p += (size_t)MPAD * H512 * 2;
    short* h1 = (short*)p; p += (size_t)MPAD * H512 * 2;
    short* G  = (short*)p; p += (size_t)MPAD * H512 * 2;
    short* xb = G;  // alias: xb dead before G is first written
    short* bfi = (short*)p; p += (size_t)512 * 256 * 2;       // frag-shuffled in_w
    short* bfc = (short*)p; p += (size_t)2 * 512 * 1024 * 2;  // frag-shuffled fused conv
    short* bfo = (short*)p; p += (size_t)256 * 512 * 2;       // frag-shuffled out_w
    float* deg  = (float*)p; p += (size_t)N * 4;
    float* dinv = (float*)p; p += (size_t)N * 4;
    float* ew   = (float*)p; p += (size_t)E * 4;
    int*   cnt  = (int*)p;   p += (size_t)N * 4;
    int*   ptr  = (int*)p;   p += (size_t)(N + 4) * 4;
    int*   ptr2 = (int*)p;   p += (size_t)N * 4;
    int*   esrc = (int*)p;   p += (size_t)E * 4;
    int*   bsum = (int*)p;   p += (size_t)256 * 4;
    int*   boff = (int*)p;   p += (size_t)256 * 4;

    const int NB = (N + 255) / 256;            // 196 scan blocks

    // CSR build
    hipMemsetAsync(deg, 0, (size_t)N * sizeof(float), stream);
    hipMemsetAsync(cnt, 0, (size_t)N * sizeof(int), stream);
    hist_kernel<<<(E + 255) / 256, 256, 0, stream>>>(row, col, deg, cnt, E);
    dinv_kernel<<<(N + 255) / 256, 256, 0, stream>>>(deg, dinv, N);
    bsum_kernel <<<NB, 256, 0, stream>>>(cnt, bsum, N);
    bscan_kernel<<<1, 256, 0, stream>>>(bsum, boff, NB);
    cscan_kernel<<<NB, 256, 0, stream>>>(cnt, boff, ptr, ptr2, N, NB);
    scatter_kernel<<<(E + 255) / 256, 256, 0, stream>>>(row, col, dinv, ptr2, esrc, ew, E);

    // weight frag-shuffles: in (ktot=4); conv fused batched over 4 (l,j); out (ktot=8)
    bfshuf_kernel<<<(512 * 256 / 8 + 255) / 256, 256, 0, stream>>>(in_w, bfi, 256, 512, 4, 0);
    bfshuf4_kernel<<<dim3((512 * 512 / 8 + 255) / 256, 4), 256, 0, stream>>>(conv_w, bfc);
    bfshuf_kernel<<<(512 * 256 / 8 + 255) / 256, 256, 0, stream>>>(out_w, bfo, 512, 256, 8, 0);
    xconv_kernel<<<(MPAD * 32 + 255) / 256, 256, 0, stream>>>(x, xb, N, MPAD);

    const int mt = MPAD / 128;                 // 391

    // h0 = silu(x @ in_w + in_b)        K=256
    mfma_gemm<1, 0><<<dim3(4 * mt), 256, 0, stream>>>(
        xb, xb, 256, 256, bfi, h0, H512, in_b, N, 256, 4);

    short* hc = h0;
    short* hn = h1;
    for (int l = 0; l < 2; ++l) {
        // G = Lhat @ hc  (gather, zero-pads rows >= N)
        gather_kernel<<<(MPAD + 3) / 4, 256, 0, stream>>>(ptr, esrc, ew, hc, G, N, MPAD);
        // hn = silu([hc | G] @ [W0;W1] + b)   K=1024, split at 512
        mfma_gemm<1, 0><<<dim3(4 * mt), 256, 0, stream>>>(
            hc, G, 512, H512, bfc + (size_t)l * 512 * 1024,
            hn, H512, conv_b + (size_t)l * H512, N, 1024, 4);
        short* tmp = hc; hc = hn; hn = tmp;
    }

    // out = hc @ out_w + out_b   (fp32, guarded)     K=512
    mfma_gemm<0, 1><<<dim3(2 * mt), 256, 0, stream>>>(
        hc, hc, 512, H512, bfo, d_out, 256, out_b, N, 512, 2);
}